// Round 2
// baseline (292.763 us; speedup 1.0000x reference)
//
#include <hip/hip_runtime.h>
#include <hip/hip_bf16.h>

typedef unsigned short u16;
typedef __bf16 bf16x8 __attribute__((ext_vector_type(8)));
typedef float f32x4 __attribute__((ext_vector_type(4)));
typedef unsigned short u16x8 __attribute__((ext_vector_type(8)));

// round-to-nearest-even fp32 -> bf16
__device__ inline u16 f2bf(float f) {
    union { float f; unsigned u; } v; v.f = f;
    unsigned r = v.u + 0x7fffu + ((v.u >> 16) & 1u);
    return (u16)(r >> 16);
}

// async global->LDS, 16B per lane. LDS dest = wave-uniform base + lane*16.
// Integer round-trip casts: AS1 is 64-bit (same value as generic); AS3 is the
// low 32 bits of a generic LDS pointer.
__device__ __forceinline__ void gll16(const u16* g, u16* l) {
    __builtin_amdgcn_global_load_lds(
        (__attribute__((address_space(1))) void*)(unsigned long long)(void*)g,
        (__attribute__((address_space(3))) void*)(unsigned int)(unsigned long long)(void*)l,
        16, 0, 0);
}

// ---------------------------------------------------------------------------
// Convert x and 4 weights to bf16, contiguous in ws.
// ---------------------------------------------------------------------------
__global__ void convert_kernel(const float* __restrict__ x,
                               const float* __restrict__ wq, const float* __restrict__ wk,
                               const float* __restrict__ wv, const float* __restrict__ wo,
                               u16* __restrict__ dst) {
    long g = (long)blockIdx.x * blockDim.x + threadIdx.x;  // group of 4 elements
    const float* src; long base;
    const long GX = 1048576, GW = 262144;
    if (g < GX)            { src = x;  base = 0; }
    else if (g < GX + GW)  { src = wq; base = GX; }
    else if (g < GX + 2*GW){ src = wk; base = GX + GW; }
    else if (g < GX + 3*GW){ src = wv; base = GX + 2*GW; }
    else                   { src = wo; base = GX + 3*GW; }
    long rel = g - base;
    float4 v = reinterpret_cast<const float4*>(src)[rel];
    ushort4 o;
    o.x = f2bf(v.x); o.y = f2bf(v.y); o.z = f2bf(v.z); o.w = f2bf(v.w);
    reinterpret_cast<ushort4*>(dst)[g] = o;
}

// ---------------------------------------------------------------------------
// GEMM mainloop, m97-style: 128x128 C-tile, BK=64, async global->LDS staging
// into FRAGMENT-ORDER LDS (chunk c = (m16*2+ks)*64 + lane holds
// A[row=m16*16+ln][col=ks*32+quad*8 .. +7]); all ds_read_b128 conflict-free.
// 4 waves (2x2), each 64x64 via 4x4 frags of 16x16x32 bf16.
// ---------------------------------------------------------------------------
__device__ __forceinline__ void gemm_mainloop(const u16* __restrict__ A, const u16* __restrict__ W,
                                              int t0, int n0, u16* As, u16* Bs, f32x4 acc[4][4]) {
    const int tid = threadIdx.x;
    const int wid = tid >> 6, lane = tid & 63, quad = lane >> 4, ln = lane & 15;
    const int wm = wid >> 1, wn = wid & 1;
#pragma unroll
    for (int im = 0; im < 4; im++)
#pragma unroll
        for (int in = 0; in < 4; in++) acc[im][in] = (f32x4){0.f, 0.f, 0.f, 0.f};

    // staging assignment: wave wid stages segments seg = i*4+wid (16 x 1024B per tile)
    const u16* gA[4]; const u16* gB[4]; u16* dA[4]; u16* dB[4];
#pragma unroll
    for (int i = 0; i < 4; i++) {
        int seg = i * 4 + wid;            // = m16*2 + ks
        int m16 = seg >> 1, ks = seg & 1;
        long off = (long)(m16 * 16 + ln) * 1024 + ks * 32 + quad * 8;
        gA[i] = A + (long)t0 * 1024 + off;
        gB[i] = W + (long)n0 * 1024 + off;
        dA[i] = As + seg * 512;
        dB[i] = Bs + seg * 512;
    }

    for (int k0 = 0; k0 < 1024; k0 += 64) {
#pragma unroll
        for (int i = 0; i < 4; i++) { gll16(gA[i] + k0, dA[i]); gll16(gB[i] + k0, dB[i]); }
        __syncthreads();
#pragma unroll
        for (int ks = 0; ks < 2; ks++) {
            bf16x8 af[4], bfr[4];
#pragma unroll
            for (int im = 0; im < 4; im++)
                af[im] = *reinterpret_cast<const bf16x8*>(As + (((wm * 4 + im) * 2 + ks) * 64 + lane) * 8);
#pragma unroll
            for (int in = 0; in < 4; in++)
                bfr[in] = *reinterpret_cast<const bf16x8*>(Bs + (((wn * 4 + in) * 2 + ks) * 64 + lane) * 8);
#pragma unroll
            for (int im = 0; im < 4; im++)
#pragma unroll
                for (int in = 0; in < 4; in++)
                    acc[im][in] = __builtin_amdgcn_mfma_f32_16x16x32_bf16(af[im], bfr[in], acc[im][in], 0, 0, 0);
        }
        __syncthreads();
    }
}

// ---------------------------------------------------------------------------
// QKV projection. z = 0:q, 1:k, 2:v.
//   q_ws/k_ws: [bh][s][64] bf16 (q pre-scaled by log2e/8 for exp2 softmax)
//   v_ws:      [bh][64][s] bf16 (transposed: attention PV B-frags contiguous)
// ---------------------------------------------------------------------------
__global__ void qkv_gemm(const u16* __restrict__ x_bf,
                         const u16* __restrict__ wq, const u16* __restrict__ wk, const u16* __restrict__ wv,
                         const float* __restrict__ sq, const float* __restrict__ sk, const float* __restrict__ sv,
                         const float* __restrict__ bq, const float* __restrict__ bk, const float* __restrict__ bv,
                         u16* __restrict__ q_ws, u16* __restrict__ k_ws, u16* __restrict__ v_ws) {
    __shared__ alignas(16) u16 As[8192];
    __shared__ alignas(16) u16 Bs[8192];
    const int z = blockIdx.z;
    const u16* W    = (z == 0) ? wq : (z == 1) ? wk : wv;
    const float* sp = (z == 0) ? sq : (z == 1) ? sk : sv;
    const float* bp = (z == 0) ? bq : (z == 1) ? bk : bv;
    u16* dst = (z == 0) ? q_ws : (z == 1) ? k_ws : v_ws;
    const float extra = (z == 0) ? 0.125f * 1.44269504f : 1.0f;  // 1/sqrt(64) * log2(e)
    const int t0 = blockIdx.x * 128, n0 = blockIdx.y * 128;

    f32x4 acc[4][4];
    gemm_mainloop(x_bf, W, t0, n0, As, Bs, acc);

    const int tid = threadIdx.x;
    const int wid = tid >> 6, lane = tid & 63, quad = lane >> 4, ln = lane & 15;
    const int wm = wid >> 1, wn = wid & 1;
    const float s = sp[0] * extra;
#pragma unroll
    for (int in = 0; in < 4; in++) {
        int col = n0 + wn * 64 + in * 16 + ln;
        float bias = bp[col] * extra;
        int h = col >> 6, d = col & 63;
#pragma unroll
        for (int im = 0; im < 4; im++) {
            int rbase = t0 + wm * 64 + im * 16 + quad * 4;
#pragma unroll
            for (int j = 0; j < 4; j++) {
                int t = rbase + j;
                int b = t >> 11, ss = t & 2047;
                int bh = b * 16 + h;
                float val = acc[im][in][j] * s + bias;
                long idx = (z < 2) ? ((long)(bh * 2048 + ss) * 64 + d)
                                   : ((long)(bh * 64 + d) * 2048 + ss);
                dst[idx] = f2bf(val);
            }
        }
    }
}

// ---------------------------------------------------------------------------
// Attention: per (q-tile of 64, bh). No-max softmax (scores bounded):
// accumulate exp2(s')@V unnormalized (q pre-scaled by log2e/8); denominator
// via ones-row tile appended to V^T (MFMA pipe, not VALU).
// All LDS in fragment order; K/V staged via global_load_lds.
// ---------------------------------------------------------------------------
__global__ void attn_kernel(const u16* __restrict__ q_ws, const u16* __restrict__ k_ws,
                            const u16* __restrict__ v_ws, u16* __restrict__ ctx) {
    __shared__ alignas(16) u16 Kt[8 * 512];      // segs (k8*2+ks): K[key=k8*16+ln][d=ks*32+quad*8..]
    __shared__ alignas(16) u16 Vt[10 * 512];     // segs (dt*2+st): V^T[d=dt*16+ln][key=st*32+quad*8..]; dt=4 = ones row
    __shared__ alignas(16) u16 Pt[4][1024];      // per-wave, segs (st): P[q=ln][key=st*32+quad*8..]

    const int tid = threadIdx.x;
    const int wid = tid >> 6, lane = tid & 63, quad = lane >> 4, ln = lane & 15;
    const int bh = blockIdx.y;
    const int q0 = blockIdx.x * 64;
    const u16* qbase = q_ws + (long)bh * 2048 * 64;
    const u16* kbase = k_ws + (long)bh * 2048 * 64;
    const u16* vbase = v_ws + (long)bh * 64 * 2048;

    // ones/zeros tail of Vt (segments 8,9: d = 64+ln; ones iff ln==0)
    for (int e = tid; e < 1024; e += 256) {
        int lp = (e >> 3) & 63;
        Vt[4096 + e] = ((lp & 15) == 0) ? (u16)0x3F80 : (u16)0;
    }

    // Q fragments in registers for the whole K loop
    bf16x8 aq[2];
#pragma unroll
    for (int ks = 0; ks < 2; ks++)
        aq[ks] = *reinterpret_cast<const bf16x8*>(
            qbase + (long)(q0 + wid * 16 + ln) * 64 + ks * 32 + quad * 8);

    // staging: 16 segments / 4 waves; si<8 -> Kt seg si, else Vt seg si-8
    const u16* sbase[4]; int smul[4]; u16* sdst[4];
#pragma unroll
    for (int i = 0; i < 4; i++) {
        int si = i * 4 + wid;
        if (si < 8) {
            int k8 = si >> 1, ks = si & 1;
            sbase[i] = kbase + (long)(k8 * 16 + ln) * 64 + ks * 32 + quad * 8;
            smul[i] = 64;
            sdst[i] = Kt + si * 512;
        } else {
            int sv2 = si - 8; int dt = sv2 >> 1, st = sv2 & 1;
            sbase[i] = vbase + (long)(dt * 16 + ln) * 2048 + st * 32 + quad * 8;
            smul[i] = 1;
            sdst[i] = Vt + sv2 * 512;
        }
    }

    f32x4 acc_o[4];
    f32x4 acc_l = (f32x4){0.f, 0.f, 0.f, 0.f};
#pragma unroll
    for (int dt = 0; dt < 4; dt++) acc_o[dt] = (f32x4){0.f, 0.f, 0.f, 0.f};

    for (int kt = 0; kt < 2048; kt += 64) {
#pragma unroll
        for (int i = 0; i < 4; i++) gll16(sbase[i] + (long)kt * smul[i], sdst[i]);
        __syncthreads();

        // S' = Q' K^T (includes log2e/sqrt(64) via q pre-scale)
        f32x4 sfr[4];
#pragma unroll
        for (int k8 = 0; k8 < 4; k8++) {
            bf16x8 b0 = *reinterpret_cast<const bf16x8*>(Kt + ((k8 * 2 + 0) * 64 + lane) * 8);
            bf16x8 b1 = *reinterpret_cast<const bf16x8*>(Kt + ((k8 * 2 + 1) * 64 + lane) * 8);
            f32x4 t = (f32x4){0.f, 0.f, 0.f, 0.f};
            t = __builtin_amdgcn_mfma_f32_16x16x32_bf16(aq[0], b0, t, 0, 0, 0);
            t = __builtin_amdgcn_mfma_f32_16x16x32_bf16(aq[1], b1, t, 0, 0, 0);
            sfr[k8] = t;
        }

        // P = exp2(S') -> wave-private Pt in A-fragment order
#pragma unroll
        for (int k8 = 0; k8 < 4; k8++)
#pragma unroll
            for (int j = 0; j < 4; j++) {
                float p = exp2f(sfr[k8][j]);
                int kh = k8 * 16 + ln;
                int el = ((kh >> 5) * 64 + ((kh & 31) >> 3) * 16 + quad * 4 + j) * 8 + (kh & 7);
                Pt[wid][el] = f2bf(p);
            }

        // O += P V ; l += P 1  (dt==4 = ones row of Vt)
#pragma unroll
        for (int st = 0; st < 2; st++) {
            bf16x8 ap = *reinterpret_cast<const bf16x8*>(Pt[wid] + (st * 64 + lane) * 8);
#pragma unroll
            for (int dt = 0; dt < 5; dt++) {
                bf16x8 bv = *reinterpret_cast<const bf16x8*>(Vt + ((dt * 2 + st) * 64 + lane) * 8);
                if (dt < 4)
                    acc_o[dt] = __builtin_amdgcn_mfma_f32_16x16x32_bf16(ap, bv, acc_o[dt], 0, 0, 0);
                else
                    acc_l = __builtin_amdgcn_mfma_f32_16x16x32_bf16(ap, bv, acc_l, 0, 0, 0);
            }
        }
        __syncthreads();
    }

    // normalize and write ctx [t][h*64+d] bf16
    const int b = bh >> 4, h = bh & 15;
#pragma unroll
    for (int j = 0; j < 4; j++) {
        float l = __shfl(acc_l[j], quad << 4, 64);  // denom lives in col 0 (ln==0)
        float rinv = 1.0f / l;
        int t = b * 2048 + q0 + wid * 16 + quad * 4 + j;
#pragma unroll
        for (int dt = 0; dt < 4; dt++)
            ctx[(long)t * 1024 + h * 64 + dt * 16 + ln] = f2bf(acc_o[dt][j] * rinv);
    }
}

// ---------------------------------------------------------------------------
// Output projection: d_out[t][o] = ctx @ wo^T * s_o + b_o  (fp32 out)
// ---------------------------------------------------------------------------
__global__ void o_gemm(const u16* __restrict__ ctx, const u16* __restrict__ wo,
                       const float* __restrict__ so, const float* __restrict__ bo,
                       float* __restrict__ out) {
    __shared__ alignas(16) u16 As[8192];
    __shared__ alignas(16) u16 Bs[8192];
    const int t0 = blockIdx.x * 128, n0 = blockIdx.y * 128;
    f32x4 acc[4][4];
    gemm_mainloop(ctx, wo, t0, n0, As, Bs, acc);

    const int tid = threadIdx.x;
    const int wid = tid >> 6, lane = tid & 63, quad = lane >> 4, ln = lane & 15;
    const int wm = wid >> 1, wn = wid & 1;
    const float s = so[0];
#pragma unroll
    for (int in = 0; in < 4; in++) {
        int col = n0 + wn * 64 + in * 16 + ln;
        float bias = bo[col];
#pragma unroll
        for (int im = 0; im < 4; im++) {
            int rbase = t0 + wm * 64 + im * 16 + quad * 4;
#pragma unroll
            for (int j = 0; j < 4; j++)
                out[(long)(rbase + j) * 1024 + col] = acc[im][in][j] * s + bias;
        }
    }
}

// ---------------------------------------------------------------------------
extern "C" void kernel_launch(void* const* d_in, const int* in_sizes, int n_in,
                              void* d_out, int out_size, void* d_ws, size_t ws_size,
                              hipStream_t stream) {
    const float* x   = (const float*)d_in[0];
    const float* s_q = (const float*)d_in[2];
    const float* b_q = (const float*)d_in[3];
    const float* s_k = (const float*)d_in[5];
    const float* b_k = (const float*)d_in[6];
    const float* s_v = (const float*)d_in[8];
    const float* b_v = (const float*)d_in[9];
    const float* s_o = (const float*)d_in[11];
    const float* b_o = (const float*)d_in[12];
    const float* w_q = (const float*)d_in[1];
    const float* w_k = (const float*)d_in[4];
    const float* w_v = (const float*)d_in[7];
    const float* w_o = (const float*)d_in[10];

    if (ws_size < (size_t)50331648) return;  // need 48 MB of scratch

    u16* ws     = (u16*)d_ws;
    u16* x_bf   = ws;                    // 4096*1024
    u16* wq_bf  = x_bf  + 4194304;       // 1024*1024 each
    u16* wk_bf  = wq_bf + 1048576;
    u16* wv_bf  = wk_bf + 1048576;
    u16* wo_bf  = wv_bf + 1048576;
    u16* q_ws   = wo_bf + 1048576;       // [32 bh][2048 s][64 d]
    u16* k_ws   = q_ws  + 4194304;
    u16* v_ws   = k_ws  + 4194304;       // [32 bh][64 d][2048 s]
    u16* ctx_ws = v_ws  + 4194304;       // [4096 t][1024]

    convert_kernel<<<dim3(8192), dim3(256), 0, stream>>>(x, w_q, w_k, w_v, w_o, ws);
    qkv_gemm<<<dim3(32, 8, 3), dim3(256), 0, stream>>>(x_bf, wq_bf, wk_bf, wv_bf,
                                                       s_q, s_k, s_v, b_q, b_k, b_v,
                                                       q_ws, k_ws, v_ws);
    attn_kernel<<<dim3(32, 32), dim3(256), 0, stream>>>(q_ws, k_ws, v_ws, ctx_ws);
    o_gemm<<<dim3(32, 8), dim3(256), 0, stream>>>(ctx_ws, wo_bf, s_o, b_o, (float*)d_out);
}

// Round 4
// 254.548 us; speedup vs baseline: 1.1501x; 1.1501x over previous
//
#include <hip/hip_runtime.h>
#include <hip/hip_bf16.h>

typedef unsigned short u16;
typedef __bf16 bf16x8 __attribute__((ext_vector_type(8)));
typedef float f32x4 __attribute__((ext_vector_type(4)));
typedef unsigned short u16x8 __attribute__((ext_vector_type(8)));
typedef unsigned short u16x4 __attribute__((ext_vector_type(4)));
typedef short s16x4 __attribute__((ext_vector_type(4)));
typedef unsigned u32x2 __attribute__((ext_vector_type(2)));

// 16x16x16 bf16 MFMA (K=16). Host pass never evaluates __has_builtin against
// gfx950, so dispatch must live behind __HIP_DEVICE_COMPILE__ (R3 lesson).
__device__ __forceinline__ f32x4 mfma_k16(s16x4 a, s16x4 b, f32x4 c) {
#if defined(__HIP_DEVICE_COMPILE__)
#if __has_builtin(__builtin_amdgcn_mfma_f32_16x16x16bf16_1k)
    return __builtin_amdgcn_mfma_f32_16x16x16bf16_1k(a, b, c, 0, 0, 0);
#else
    f32x4 d;
    asm volatile("v_mfma_f32_16x16x16_bf16 %0, %1, %2, %3"
                 : "=v"(d) : "v"(a), "v"(b), "0"(c));
    return d;
#endif
#else
    (void)a; (void)b;
    return c;  // host pass: parsed, never executed
#endif
}

// round-to-nearest-even fp32 -> bf16
__device__ inline u16 f2bf(float f) {
    union { float f; unsigned u; } v; v.f = f;
    unsigned r = v.u + 0x7fffu + ((v.u >> 16) & 1u);
    return (u16)(r >> 16);
}

// async global->LDS, 16B/lane; LDS dest = wave-uniform base + lane*16.
__device__ __forceinline__ void gll16(const u16* g, u16* l) {
    __builtin_amdgcn_global_load_lds(
        (__attribute__((address_space(1))) void*)(unsigned long long)(void*)g,
        (__attribute__((address_space(3))) void*)(unsigned int)(unsigned long long)(void*)l,
        16, 0, 0);
}

// ---------------------------------------------------------------------------
// Convert x and 4 weights to bf16, contiguous in ws.
// ---------------------------------------------------------------------------
__global__ void convert_kernel(const float* __restrict__ x,
                               const float* __restrict__ wq, const float* __restrict__ wk,
                               const float* __restrict__ wv, const float* __restrict__ wo,
                               u16* __restrict__ dst) {
    long g = (long)blockIdx.x * blockDim.x + threadIdx.x;  // group of 4 elements
    const float* src; long base;
    const long GX = 1048576, GW = 262144;
    if (g < GX)            { src = x;  base = 0; }
    else if (g < GX + GW)  { src = wq; base = GX; }
    else if (g < GX + 2*GW){ src = wk; base = GX + GW; }
    else if (g < GX + 3*GW){ src = wv; base = GX + 2*GW; }
    else                   { src = wo; base = GX + 3*GW; }
    long rel = g - base;
    float4 v = reinterpret_cast<const float4*>(src)[rel];
    ushort4 o;
    o.x = f2bf(v.x); o.y = f2bf(v.y); o.z = f2bf(v.z); o.w = f2bf(v.w);
    reinterpret_cast<ushort4*>(dst)[g] = o;
}

// ---------------------------------------------------------------------------
// GEMM mainloop: 128x128 C-tile, BK=64, global_load_lds staging with
// XOR-swizzle: lane rr=lane>>3, c8=lane&7 reads global chunk c8^rr =>
// each instruction = 8 contiguous 128B row-segments (m97 coalescing), and
// LDS holds A[row][k] at el = row*64 + ((k>>3)^(row&7))*8 + (k&7) => frag
// ds_read_b128 balanced 8-accesses/bank (the b128 floor).
// ---------------------------------------------------------------------------
__device__ __forceinline__ void gemm_mainloop(const u16* __restrict__ A, const u16* __restrict__ W,
                                              int t0, int n0, u16* As, u16* Bs, f32x4 acc[4][4]) {
    const int tid = threadIdx.x;
    const int wid = tid >> 6, lane = tid & 63, quad = lane >> 4, ln = lane & 15;
    const int wm = wid >> 1, wn = wid & 1;
    const int rr = lane >> 3, c8 = lane & 7;
    const int ln7 = ln & 7;
#pragma unroll
    for (int im = 0; im < 4; im++)
#pragma unroll
        for (int in = 0; in < 4; in++) acc[im][in] = (f32x4){0.f, 0.f, 0.f, 0.f};

    // wave wid stages segments seg = i*4+wid (each = rows seg*8..seg*8+7)
    const u16* gA[4]; const u16* gB[4]; u16* dA[4]; u16* dB[4];
#pragma unroll
    for (int i = 0; i < 4; i++) {
        int seg = i * 4 + wid;
        long off = (long)(seg * 8 + rr) * 1024 + (c8 ^ rr) * 8;
        gA[i] = A + (long)t0 * 1024 + off;
        gB[i] = W + (long)n0 * 1024 + off;
        dA[i] = As + seg * 512;
        dB[i] = Bs + seg * 512;
    }

    for (int k0 = 0; k0 < 1024; k0 += 64) {
#pragma unroll
        for (int i = 0; i < 4; i++) { gll16(gA[i] + k0, dA[i]); gll16(gB[i] + k0, dB[i]); }
        __syncthreads();
#pragma unroll
        for (int ks = 0; ks < 2; ks++) {
            bf16x8 af[4], bfr[4];
#pragma unroll
            for (int im = 0; im < 4; im++)
                af[im] = *reinterpret_cast<const bf16x8*>(
                    As + (wm * 64 + im * 16 + ln) * 64 + (((ks * 4 + quad) ^ ln7) * 8));
#pragma unroll
            for (int in = 0; in < 4; in++)
                bfr[in] = *reinterpret_cast<const bf16x8*>(
                    Bs + (wn * 64 + in * 16 + ln) * 64 + (((ks * 4 + quad) ^ ln7) * 8));
#pragma unroll
            for (int im = 0; im < 4; im++)
#pragma unroll
                for (int in = 0; in < 4; in++)
                    acc[im][in] = __builtin_amdgcn_mfma_f32_16x16x32_bf16(af[im], bfr[in], acc[im][in], 0, 0, 0);
        }
        __syncthreads();
    }
}

// ---------------------------------------------------------------------------
// QKV projection. z = 0:q, 1:k, 2:v.
//   q_ws/k_ws: [bh][s][64] bf16 (q pre-scaled by log2e/8 for exp2 softmax)
//   v_ws:      [bh][64][s] bf16 (transposed)
// ---------------------------------------------------------------------------
__global__ void qkv_gemm(const u16* __restrict__ x_bf,
                         const u16* __restrict__ wq, const u16* __restrict__ wk, const u16* __restrict__ wv,
                         const float* __restrict__ sq, const float* __restrict__ sk, const float* __restrict__ sv,
                         const float* __restrict__ bq, const float* __restrict__ bk, const float* __restrict__ bv,
                         u16* __restrict__ q_ws, u16* __restrict__ k_ws, u16* __restrict__ v_ws) {
    __shared__ alignas(16) u16 As[8192];
    __shared__ alignas(16) u16 Bs[8192];
    const int z = blockIdx.z;
    const u16* W    = (z == 0) ? wq : (z == 1) ? wk : wv;
    const float* sp = (z == 0) ? sq : (z == 1) ? sk : sv;
    const float* bp = (z == 0) ? bq : (z == 1) ? bk : bv;
    u16* dst = (z == 0) ? q_ws : (z == 1) ? k_ws : v_ws;
    const float extra = (z == 0) ? 0.125f * 1.44269504f : 1.0f;  // 1/sqrt(64) * log2(e)
    const int t0 = blockIdx.x * 128, n0 = blockIdx.y * 128;

    f32x4 acc[4][4];
    gemm_mainloop(x_bf, W, t0, n0, As, Bs, acc);

    const int tid = threadIdx.x;
    const int wid = tid >> 6, lane = tid & 63, quad = lane >> 4, ln = lane & 15;
    const int wm = wid >> 1, wn = wid & 1;
    const float s = sp[0] * extra;
#pragma unroll
    for (int in = 0; in < 4; in++) {
        int col = n0 + wn * 64 + in * 16 + ln;
        float bias = bp[col] * extra;
        int h = col >> 6, d = col & 63;
#pragma unroll
        for (int im = 0; im < 4; im++) {
            int rbase = t0 + wm * 64 + im * 16 + quad * 4;
#pragma unroll
            for (int j = 0; j < 4; j++) {
                int t = rbase + j;
                int b = t >> 11, ss = t & 2047;
                int bh = b * 16 + h;
                float val = acc[im][in][j] * s + bias;
                long idx = (z < 2) ? ((long)(bh * 2048 + ss) * 64 + d)
                                   : ((long)(bh * 64 + d) * 2048 + ss);
                dst[idx] = f2bf(val);
            }
        }
    }
}

// ---------------------------------------------------------------------------
// Attention, register-resident P:
//   S^T = K Q^T   (16x16x32; A=K-frag from LDS, B=Q-frag in regs)
//   P   = exp2(S') packed to bf16 pairs in the S^T C-layout, which IS the
//         B-operand layout of 16x16x16 (k = quad*4+j == C row quad*4+reg)
//   O^T = V^T P^T (16x16x16; A=V^T-frag from LDS, B=P from regs)
//   denom via constant ones A-frag -> every lane holds l[q] (no shuffles).
// No P LDS round-trip, no-max softmax (scores bounded by construction).
// ---------------------------------------------------------------------------
__global__ void attn_kernel(const u16* __restrict__ q_ws, const u16* __restrict__ k_ws,
                            const u16* __restrict__ v_ws, u16* __restrict__ ctx) {
    __shared__ alignas(16) u16 Kt[4096];   // K[key][d], swizzled rows (64x64)
    __shared__ alignas(16) u16 Vt[4096];   // V^T[d][key], swizzled rows (64x64)

    const int tid = threadIdx.x;
    const int wid = tid >> 6, lane = tid & 63, quad = lane >> 4, ln = lane & 15;
    const int rr = lane >> 3, c8 = lane & 7;
    const int ln7 = ln & 7;
    const int bh = blockIdx.y;
    const int q0 = blockIdx.x * 128;
    const u16* qbase = q_ws + (long)bh * 2048 * 64;
    const u16* kbase = k_ws + (long)bh * 2048 * 64;
    const u16* vbase = v_ws + (long)bh * 64 * 2048;

    // Q fragments (B-operand) in registers for the whole loop; 32 q per wave
    bf16x8 bq[2][2];
#pragma unroll
    for (int qt = 0; qt < 2; qt++)
#pragma unroll
        for (int ks = 0; ks < 2; ks++)
            bq[qt][ks] = *reinterpret_cast<const bf16x8*>(
                qbase + (long)(q0 + wid * 32 + qt * 16 + ln) * 64 + ks * 32 + quad * 8);

    // staging: 16 segments (K 0..7, V 8..15), wave wid does si = i*4+wid
    const u16* sbase[4]; int smul[4]; u16* sdst[4];
#pragma unroll
    for (int i = 0; i < 4; i++) {
        int si = i * 4 + wid;
        if (si < 8) {   // K rows = keys si*8+rr, chunks over d
            sbase[i] = kbase + (long)(si * 8 + rr) * 64 + (c8 ^ rr) * 8;
            smul[i] = 64;                    // advance 64 els per key step
            sdst[i] = Kt + si * 512;
        } else {        // V^T rows = d, chunks over keys
            int sv2 = si - 8;
            sbase[i] = vbase + (long)(sv2 * 8 + rr) * 2048 + (c8 ^ rr) * 8;
            smul[i] = 1;
            sdst[i] = Vt + sv2 * 512;
        }
    }

    f32x4 acc_o[4][2];
    f32x4 acc_l[2];
#pragma unroll
    for (int qt = 0; qt < 2; qt++) {
        acc_l[qt] = (f32x4){0.f, 0.f, 0.f, 0.f};
#pragma unroll
        for (int dt = 0; dt < 4; dt++) acc_o[dt][qt] = (f32x4){0.f, 0.f, 0.f, 0.f};
    }

    const s16x4 ones = {0x3F80, 0x3F80, 0x3F80, 0x3F80};  // bf16 1.0 x4

    for (int kt = 0; kt < 2048; kt += 64) {
#pragma unroll
        for (int i = 0; i < 4; i++) gll16(sbase[i] + (long)kt * smul[i], sdst[i]);
        __syncthreads();

        // S^T = K Q^T : C[m=key][n=q]
        f32x4 sfr[4][2];
#pragma unroll
        for (int k8 = 0; k8 < 4; k8++) {
            bf16x8 a0 = *reinterpret_cast<const bf16x8*>(Kt + (k8 * 16 + ln) * 64 + ((quad ^ ln7) * 8));
            bf16x8 a1 = *reinterpret_cast<const bf16x8*>(Kt + (k8 * 16 + ln) * 64 + (((4 + quad) ^ ln7) * 8));
#pragma unroll
            for (int qt = 0; qt < 2; qt++) {
                f32x4 t = (f32x4){0.f, 0.f, 0.f, 0.f};
                t = __builtin_amdgcn_mfma_f32_16x16x32_bf16(a0, bq[qt][0], t, 0, 0, 0);
                t = __builtin_amdgcn_mfma_f32_16x16x32_bf16(a1, bq[qt][1], t, 0, 0, 0);
                sfr[k8][qt] = t;
            }
        }

        // P = exp2(S'), packed bf16 pairs == 16x16x16 B-operand for
        // keys k8*16 + quad*4 + {0..3}, q = qt*16+ln.
        u32x2 pk[4][2];
#pragma unroll
        for (int k8 = 0; k8 < 4; k8++)
#pragma unroll
            for (int qt = 0; qt < 2; qt++) {
                unsigned lo0 = f2bf(exp2f(sfr[k8][qt][0]));
                unsigned hi0 = f2bf(exp2f(sfr[k8][qt][1]));
                unsigned lo1 = f2bf(exp2f(sfr[k8][qt][2]));
                unsigned hi1 = f2bf(exp2f(sfr[k8][qt][3]));
                pk[k8][qt] = (u32x2){lo0 | (hi0 << 16), lo1 | (hi1 << 16)};
            }

        // O^T += V^T P^T ; l += 1 P^T   (K=16 per step t, keys t*16..t*16+15)
#pragma unroll
        for (int t = 0; t < 4; t++) {
            union { u32x2 u; s16x4 s; } b0, b1;
            b0.u = pk[t][0];
            b1.u = pk[t][1];
            acc_l[0] = mfma_k16(ones, b0.s, acc_l[0]);
            acc_l[1] = mfma_k16(ones, b1.s, acc_l[1]);
#pragma unroll
            for (int dt = 0; dt < 4; dt++) {
                // A[m=d=dt*16+ln][k=key=t*16+quad*4+j]
                s16x4 va = *reinterpret_cast<const s16x4*>(
                    Vt + (dt * 16 + ln) * 64 + (((t * 2 + (quad >> 1)) ^ ln7) * 8) + (quad & 1) * 4);
                acc_o[dt][0] = mfma_k16(va, b0.s, acc_o[dt][0]);
                acc_o[dt][1] = mfma_k16(va, b1.s, acc_o[dt][1]);
            }
        }
        __syncthreads();
    }

    // O^T C-layout: lane holds q = qt*16+ln, d = dt*16+quad*4+jj; acc_l rows all = l[q]
    const int b = bh >> 4, h = bh & 15;
#pragma unroll
    for (int qt = 0; qt < 2; qt++) {
        float rinv = 1.0f / acc_l[qt][0];
        int t = b * 2048 + q0 + wid * 32 + qt * 16 + ln;
#pragma unroll
        for (int dt = 0; dt < 4; dt++) {
            u16x4 o;
#pragma unroll
            for (int jj = 0; jj < 4; jj++) o[jj] = f2bf(acc_o[dt][qt][jj] * rinv);
            *reinterpret_cast<u16x4*>(ctx + (long)t * 1024 + h * 64 + dt * 16 + quad * 4) = o;
        }
    }
}

// ---------------------------------------------------------------------------
// Output projection: d_out[t][o] = ctx @ wo^T * s_o + b_o  (fp32 out)
// ---------------------------------------------------------------------------
__global__ void o_gemm(const u16* __restrict__ ctx, const u16* __restrict__ wo,
                       const float* __restrict__ so, const float* __restrict__ bo,
                       float* __restrict__ out) {
    __shared__ alignas(16) u16 As[8192];
    __shared__ alignas(16) u16 Bs[8192];
    const int t0 = blockIdx.x * 128, n0 = blockIdx.y * 128;
    f32x4 acc[4][4];
    gemm_mainloop(ctx, wo, t0, n0, As, Bs, acc);

    const int tid = threadIdx.x;
    const int wid = tid >> 6, lane = tid & 63, quad = lane >> 4, ln = lane & 15;
    const int wm = wid >> 1, wn = wid & 1;
    const float s = so[0];
#pragma unroll
    for (int in = 0; in < 4; in++) {
        int col = n0 + wn * 64 + in * 16 + ln;
        float bias = bo[col];
#pragma unroll
        for (int im = 0; im < 4; im++) {
            int rbase = t0 + wm * 64 + im * 16 + quad * 4;
#pragma unroll
            for (int j = 0; j < 4; j++)
                out[(long)(rbase + j) * 1024 + col] = acc[im][in][j] * s + bias;
        }
    }
}

// ---------------------------------------------------------------------------
extern "C" void kernel_launch(void* const* d_in, const int* in_sizes, int n_in,
                              void* d_out, int out_size, void* d_ws, size_t ws_size,
                              hipStream_t stream) {
    const float* x   = (const float*)d_in[0];
    const float* w_q = (const float*)d_in[1];
    const float* s_q = (const float*)d_in[2];
    const float* b_q = (const float*)d_in[3];
    const float* w_k = (const float*)d_in[4];
    const float* s_k = (const float*)d_in[5];
    const float* b_k = (const float*)d_in[6];
    const float* w_v = (const float*)d_in[7];
    const float* s_v = (const float*)d_in[8];
    const float* b_v = (const float*)d_in[9];
    const float* w_o = (const float*)d_in[10];
    const float* s_o = (const float*)d_in[11];
    const float* b_o = (const float*)d_in[12];

    if (ws_size < (size_t)50331648) return;  // need 48 MB of scratch

    u16* ws     = (u16*)d_ws;
    u16* x_bf   = ws;                    // 4096*1024
    u16* wq_bf  = x_bf  + 4194304;       // 1024*1024 each
    u16* wk_bf  = wq_bf + 1048576;
    u16* wv_bf  = wk_bf + 1048576;
    u16* wo_bf  = wv_bf + 1048576;
    u16* q_ws   = wo_bf + 1048576;       // [32 bh][2048 s][64 d]
    u16* k_ws   = q_ws  + 4194304;
    u16* v_ws   = k_ws  + 4194304;       // [32 bh][64 d][2048 s]
    u16* ctx_ws = v_ws  + 4194304;       // [4096 t][1024]

    convert_kernel<<<dim3(8192), dim3(256), 0, stream>>>(x, w_q, w_k, w_v, w_o, ws);
    qkv_gemm<<<dim3(32, 8, 3), dim3(256), 0, stream>>>(x_bf, wq_bf, wk_bf, wv_bf,
                                                       s_q, s_k, s_v, b_q, b_k, b_v,
                                                       q_ws, k_ws, v_ws);
    attn_kernel<<<dim3(16, 32), dim3(256), 0, stream>>>(q_ws, k_ws, v_ws, ctx_ws);
    o_gemm<<<dim3(32, 8), dim3(256), 0, stream>>>(ctx_ws, wo_bf, s_o, b_o, (float*)d_out);
}

// Round 5
// 251.455 us; speedup vs baseline: 1.1643x; 1.0123x over previous
//
#include <hip/hip_runtime.h>
#include <hip/hip_bf16.h>

typedef unsigned short u16;
typedef __bf16 bf16x8 __attribute__((ext_vector_type(8)));
typedef float f32x4 __attribute__((ext_vector_type(4)));
typedef unsigned short u16x8 __attribute__((ext_vector_type(8)));
typedef unsigned short u16x4 __attribute__((ext_vector_type(4)));
typedef short s16x4 __attribute__((ext_vector_type(4)));
typedef unsigned u32x2 __attribute__((ext_vector_type(2)));

// 16x16x16 bf16 MFMA (K=16). Dispatch behind __HIP_DEVICE_COMPILE__ (R3 lesson:
// host pass evaluates __has_builtin against x86 and must not pick a bad name).
__device__ __forceinline__ f32x4 mfma_k16(s16x4 a, s16x4 b, f32x4 c) {
#if defined(__HIP_DEVICE_COMPILE__)
#if __has_builtin(__builtin_amdgcn_mfma_f32_16x16x16bf16_1k)
    return __builtin_amdgcn_mfma_f32_16x16x16bf16_1k(a, b, c, 0, 0, 0);
#else
    f32x4 d;
    asm volatile("v_mfma_f32_16x16x16_bf16 %0, %1, %2, %3"
                 : "=v"(d) : "v"(a), "v"(b), "0"(c));
    return d;
#endif
#else
    (void)a; (void)b;
    return c;  // host pass: parsed, never executed
#endif
}

// round-to-nearest-even fp32 -> bf16
__device__ inline u16 f2bf(float f) {
    union { float f; unsigned u; } v; v.f = f;
    unsigned r = v.u + 0x7fffu + ((v.u >> 16) & 1u);
    return (u16)(r >> 16);
}

// pack two fp32 -> one dword of two bf16 (single v_cvt_pk_bf16_f32 if present)
__device__ __forceinline__ unsigned pk_bf16(float a, float b) {
#if defined(__HIP_DEVICE_COMPILE__) && __has_builtin(__builtin_amdgcn_cvt_pk_bf16_f32)
    typedef __bf16 bf16x2_t __attribute__((ext_vector_type(2)));
    union { bf16x2_t v; unsigned u; } r;
    r.v = __builtin_amdgcn_cvt_pk_bf16_f32(a, b);
    return r.u;
#else
    return (unsigned)f2bf(a) | ((unsigned)f2bf(b) << 16);
#endif
}

// async global->LDS, 16B/lane; LDS dest = wave-uniform base + lane*16.
__device__ __forceinline__ void gll16(const u16* g, u16* l) {
    __builtin_amdgcn_global_load_lds(
        (__attribute__((address_space(1))) void*)(unsigned long long)(void*)g,
        (__attribute__((address_space(3))) void*)(unsigned int)(unsigned long long)(void*)l,
        16, 0, 0);
}

// ---------------------------------------------------------------------------
// Convert x and 4 weights to bf16, contiguous in ws.
// ---------------------------------------------------------------------------
__global__ void convert_kernel(const float* __restrict__ x,
                               const float* __restrict__ wq, const float* __restrict__ wk,
                               const float* __restrict__ wv, const float* __restrict__ wo,
                               u16* __restrict__ dst) {
    long g = (long)blockIdx.x * blockDim.x + threadIdx.x;  // group of 4 elements
    const float* src; long base;
    const long GX = 1048576, GW = 262144;
    if (g < GX)            { src = x;  base = 0; }
    else if (g < GX + GW)  { src = wq; base = GX; }
    else if (g < GX + 2*GW){ src = wk; base = GX + GW; }
    else if (g < GX + 3*GW){ src = wv; base = GX + 2*GW; }
    else                   { src = wo; base = GX + 3*GW; }
    long rel = g - base;
    float4 v = reinterpret_cast<const float4*>(src)[rel];
    ushort4 o;
    o.x = f2bf(v.x); o.y = f2bf(v.y); o.z = f2bf(v.z); o.w = f2bf(v.w);
    reinterpret_cast<ushort4*>(dst)[g] = o;
}

// ---------------------------------------------------------------------------
// GEMM mainloop, EXACT m97 structure (874 TF evidence): M-tile = IM*32,
// N-tile = 128, BK = 64. Staging is strictly linear: lane = (rr=lane>>3,
// c8=lane&7) reads row seg*8+rr, chunk c8 -> each gll16 = 8 x 128B in-order
// row segments; LDS = plain row-major [row][64]. Frag ds_read_b128 at
// (row)*64 + ks*32 + quad*8 (m97's conflict profile — tolerable, m98).
// ---------------------------------------------------------------------------
template <int IM>
__device__ __forceinline__ void gemm_mainloop(const u16* __restrict__ A, const u16* __restrict__ W,
                                              int t0, int n0, u16* As, u16* Bs,
                                              f32x4 (&acc)[IM][4]) {
    const int tid = threadIdx.x;
    const int wid = tid >> 6, lane = tid & 63, quad = lane >> 4, ln = lane & 15;
    const int wm = wid >> 1, wn = wid & 1;
    const int rr = lane >> 3, c8 = lane & 7;
#pragma unroll
    for (int im = 0; im < IM; im++)
#pragma unroll
        for (int in = 0; in < 4; in++) acc[im][in] = (f32x4){0.f, 0.f, 0.f, 0.f};

    // IM*4 A-segments then 16 B-segments; wave wid stages si = i*4+wid
    const u16* g[IM + 4]; u16* dst[IM + 4];
#pragma unroll
    for (int i = 0; i < IM + 4; i++) {
        int si = i * 4 + wid;
        if (si < IM * 4) {
            g[i]   = A + (long)(t0 + si * 8 + rr) * 1024 + c8 * 8;
            dst[i] = As + si * 512;
        } else {
            int sb = si - IM * 4;
            g[i]   = W + (long)(n0 + sb * 8 + rr) * 1024 + c8 * 8;
            dst[i] = Bs + sb * 512;
        }
    }

    for (int k0 = 0; k0 < 1024; k0 += 64) {
#pragma unroll
        for (int i = 0; i < IM + 4; i++) gll16(g[i] + k0, dst[i]);
        __syncthreads();
#pragma unroll
        for (int ks = 0; ks < 2; ks++) {
            bf16x8 af[IM], bfr[4];
#pragma unroll
            for (int im = 0; im < IM; im++)
                af[im] = *reinterpret_cast<const bf16x8*>(
                    As + (wm * (IM * 16) + im * 16 + ln) * 64 + ks * 32 + quad * 8);
#pragma unroll
            for (int in = 0; in < 4; in++)
                bfr[in] = *reinterpret_cast<const bf16x8*>(
                    Bs + (wn * 64 + in * 16 + ln) * 64 + ks * 32 + quad * 8);
#pragma unroll
            for (int im = 0; im < IM; im++)
#pragma unroll
                for (int in = 0; in < 4; in++)
                    acc[im][in] = __builtin_amdgcn_mfma_f32_16x16x32_bf16(af[im], bfr[in], acc[im][in], 0, 0, 0);
        }
        __syncthreads();
    }
}

// ---------------------------------------------------------------------------
// QKV projection (128x128 tiles). z = 0:q, 1:k, 2:v.
//   q_ws/k_ws: [bh][s][64] bf16 (q pre-scaled by log2e/8 for exp2 softmax)
//   v_ws:      [bh][64][s] bf16 (transposed)
// ---------------------------------------------------------------------------
__global__ void qkv_gemm(const u16* __restrict__ x_bf,
                         const u16* __restrict__ wq, const u16* __restrict__ wk, const u16* __restrict__ wv,
                         const float* __restrict__ sq, const float* __restrict__ sk, const float* __restrict__ sv,
                         const float* __restrict__ bq, const float* __restrict__ bk, const float* __restrict__ bv,
                         u16* __restrict__ q_ws, u16* __restrict__ k_ws, u16* __restrict__ v_ws) {
    __shared__ alignas(16) u16 As[8192];
    __shared__ alignas(16) u16 Bs[8192];
    const int z = blockIdx.z;
    const u16* W    = (z == 0) ? wq : (z == 1) ? wk : wv;
    const float* sp = (z == 0) ? sq : (z == 1) ? sk : sv;
    const float* bp = (z == 0) ? bq : (z == 1) ? bk : bv;
    u16* dst = (z == 0) ? q_ws : (z == 1) ? k_ws : v_ws;
    const float extra = (z == 0) ? 0.125f * 1.44269504f : 1.0f;  // 1/sqrt(64) * log2(e)
    const int t0 = blockIdx.x * 128, n0 = blockIdx.y * 128;

    f32x4 acc[4][4];
    gemm_mainloop<4>(x_bf, W, t0, n0, As, Bs, acc);

    const int tid = threadIdx.x;
    const int wid = tid >> 6, lane = tid & 63, quad = lane >> 4, ln = lane & 15;
    const int wm = wid >> 1, wn = wid & 1;
    const float s = sp[0] * extra;
#pragma unroll
    for (int in = 0; in < 4; in++) {
        int col = n0 + wn * 64 + in * 16 + ln;
        float bias = bp[col] * extra;
        int h = col >> 6, d = col & 63;
#pragma unroll
        for (int im = 0; im < 4; im++) {
            int rbase = t0 + wm * 64 + im * 16 + quad * 4;
#pragma unroll
            for (int j = 0; j < 4; j++) {
                int t = rbase + j;
                int b = t >> 11, ss = t & 2047;
                int bh = b * 16 + h;
                float val = acc[im][in][j] * s + bias;
                long idx = (z < 2) ? ((long)(bh * 2048 + ss) * 64 + d)
                                   : ((long)(bh * 64 + d) * 2048 + ss);
                dst[idx] = f2bf(val);
            }
        }
    }
}

// ---------------------------------------------------------------------------
// Attention (structure measured in R4; only the pack path changed):
//   S^T = K Q^T   (16x16x32; A=K-frag from LDS, B=Q-frag in regs)
//   P   = exp2(S') packed via v_cvt_pk_bf16_f32 into the S^T C-layout ==
//         B-operand layout of 16x16x16
//   O^T = V^T P^T (16x16x16; A=V^T-frag from LDS, B=P from regs)
//   denom via constant ones A-frag. No P LDS round-trip; no-max softmax.
// ---------------------------------------------------------------------------
__global__ void attn_kernel(const u16* __restrict__ q_ws, const u16* __restrict__ k_ws,
                            const u16* __restrict__ v_ws, u16* __restrict__ ctx) {
    __shared__ alignas(16) u16 Kt[4096];   // K[key][d], swizzled rows (64x64)
    __shared__ alignas(16) u16 Vt[4096];   // V^T[d][key], swizzled rows (64x64)

    const int tid = threadIdx.x;
    const int wid = tid >> 6, lane = tid & 63, quad = lane >> 4, ln = lane & 15;
    const int rr = lane >> 3, c8 = lane & 7;
    const int ln7 = ln & 7;
    const int bh = blockIdx.y;
    const int q0 = blockIdx.x * 128;
    const u16* qbase = q_ws + (long)bh * 2048 * 64;
    const u16* kbase = k_ws + (long)bh * 2048 * 64;
    const u16* vbase = v_ws + (long)bh * 64 * 2048;

    // Q fragments (B-operand) in registers for the whole loop; 32 q per wave
    bf16x8 bq[2][2];
#pragma unroll
    for (int qt = 0; qt < 2; qt++)
#pragma unroll
        for (int ks = 0; ks < 2; ks++)
            bq[qt][ks] = *reinterpret_cast<const bf16x8*>(
                qbase + (long)(q0 + wid * 32 + qt * 16 + ln) * 64 + ks * 32 + quad * 8);

    // staging: 16 segments (K 0..7, V 8..15), wave wid does si = i*4+wid
    const u16* sbase[4]; int smul[4]; u16* sdst[4];
#pragma unroll
    for (int i = 0; i < 4; i++) {
        int si = i * 4 + wid;
        if (si < 8) {   // K rows = keys si*8+rr, chunks over d
            sbase[i] = kbase + (long)(si * 8 + rr) * 64 + (c8 ^ rr) * 8;
            smul[i] = 64;                    // advance 64 els per key step
            sdst[i] = Kt + si * 512;
        } else {        // V^T rows = d, chunks over keys
            int sv2 = si - 8;
            sbase[i] = vbase + (long)(sv2 * 8 + rr) * 2048 + (c8 ^ rr) * 8;
            smul[i] = 1;
            sdst[i] = Vt + sv2 * 512;
        }
    }

    f32x4 acc_o[4][2];
    f32x4 acc_l[2];
#pragma unroll
    for (int qt = 0; qt < 2; qt++) {
        acc_l[qt] = (f32x4){0.f, 0.f, 0.f, 0.f};
#pragma unroll
        for (int dt = 0; dt < 4; dt++) acc_o[dt][qt] = (f32x4){0.f, 0.f, 0.f, 0.f};
    }

    const s16x4 ones = {0x3F80, 0x3F80, 0x3F80, 0x3F80};  // bf16 1.0 x4

    for (int kt = 0; kt < 2048; kt += 64) {
#pragma unroll
        for (int i = 0; i < 4; i++) gll16(sbase[i] + (long)kt * smul[i], sdst[i]);
        __syncthreads();

        // S^T = K Q^T : C[m=key][n=q]
        f32x4 sfr[4][2];
#pragma unroll
        for (int k8 = 0; k8 < 4; k8++) {
            bf16x8 a0 = *reinterpret_cast<const bf16x8*>(Kt + (k8 * 16 + ln) * 64 + ((quad ^ ln7) * 8));
            bf16x8 a1 = *reinterpret_cast<const bf16x8*>(Kt + (k8 * 16 + ln) * 64 + (((4 + quad) ^ ln7) * 8));
#pragma unroll
            for (int qt = 0; qt < 2; qt++) {
                f32x4 t = (f32x4){0.f, 0.f, 0.f, 0.f};
                t = __builtin_amdgcn_mfma_f32_16x16x32_bf16(a0, bq[qt][0], t, 0, 0, 0);
                t = __builtin_amdgcn_mfma_f32_16x16x32_bf16(a1, bq[qt][1], t, 0, 0, 0);
                sfr[k8][qt] = t;
            }
        }

        // P = exp2(S'), packed bf16 pairs == 16x16x16 B-operand for
        // keys k8*16 + quad*4 + {0..3}, q = qt*16+ln.
        u32x2 pk[4][2];
#pragma unroll
        for (int k8 = 0; k8 < 4; k8++)
#pragma unroll
            for (int qt = 0; qt < 2; qt++) {
                unsigned lo = pk_bf16(exp2f(sfr[k8][qt][0]), exp2f(sfr[k8][qt][1]));
                unsigned hi = pk_bf16(exp2f(sfr[k8][qt][2]), exp2f(sfr[k8][qt][3]));
                pk[k8][qt] = (u32x2){lo, hi};
            }

        // O^T += V^T P^T ; l += 1 P^T   (K=16 per step t, keys t*16..t*16+15)
#pragma unroll
        for (int t = 0; t < 4; t++) {
            union { u32x2 u; s16x4 s; } b0, b1;
            b0.u = pk[t][0];
            b1.u = pk[t][1];
            acc_l[0] = mfma_k16(ones, b0.s, acc_l[0]);
            acc_l[1] = mfma_k16(ones, b1.s, acc_l[1]);
#pragma unroll
            for (int dt = 0; dt < 4; dt++) {
                // A[m=d=dt*16+ln][k=key=t*16+quad*4+j]
                s16x4 va = *reinterpret_cast<const s16x4*>(
                    Vt + (dt * 16 + ln) * 64 + (((t * 2 + (quad >> 1)) ^ ln7) * 8) + (quad & 1) * 4);
                acc_o[dt][0] = mfma_k16(va, b0.s, acc_o[dt][0]);
                acc_o[dt][1] = mfma_k16(va, b1.s, acc_o[dt][1]);
            }
        }
        __syncthreads();
    }

    // O^T C-layout: lane holds q = qt*16+ln, d = dt*16+quad*4+jj; acc_l rows all = l[q]
    const int b = bh >> 4, h = bh & 15;
#pragma unroll
    for (int qt = 0; qt < 2; qt++) {
        float rinv = 1.0f / acc_l[qt][0];
        int t = b * 2048 + q0 + wid * 32 + qt * 16 + ln;
#pragma unroll
        for (int dt = 0; dt < 4; dt++) {
            u16x4 o;
#pragma unroll
            for (int jj = 0; jj < 4; jj++) o[jj] = f2bf(acc_o[dt][qt][jj] * rinv);
            *reinterpret_cast<u16x4*>(ctx + (long)t * 1024 + h * 64 + dt * 16 + quad * 4) = o;
        }
    }
}

// ---------------------------------------------------------------------------
// Output projection, 64x128 tiles (grid 64x8 = 512 blocks = 2/CU):
// d_out[t][o] = ctx @ wo^T * s_o + b_o  (fp32 out)
// ---------------------------------------------------------------------------
__global__ void o_gemm(const u16* __restrict__ ctx, const u16* __restrict__ wo,
                       const float* __restrict__ so, const float* __restrict__ bo,
                       float* __restrict__ out) {
    __shared__ alignas(16) u16 As[4096];
    __shared__ alignas(16) u16 Bs[8192];
    const int t0 = blockIdx.x * 64, n0 = blockIdx.y * 128;
    f32x4 acc[2][4];
    gemm_mainloop<2>(ctx, wo, t0, n0, As, Bs, acc);

    const int tid = threadIdx.x;
    const int wid = tid >> 6, lane = tid & 63, quad = lane >> 4, ln = lane & 15;
    const int wm = wid >> 1, wn = wid & 1;
    const float s = so[0];
#pragma unroll
    for (int in = 0; in < 4; in++) {
        int col = n0 + wn * 64 + in * 16 + ln;
        float bias = bo[col];
#pragma unroll
        for (int im = 0; im < 2; im++) {
            int rbase = t0 + wm * 32 + im * 16 + quad * 4;
#pragma unroll
            for (int j = 0; j < 4; j++)
                out[(long)(rbase + j) * 1024 + col] = acc[im][in][j] * s + bias;
        }
    }
}

// ---------------------------------------------------------------------------
extern "C" void kernel_launch(void* const* d_in, const int* in_sizes, int n_in,
                              void* d_out, int out_size, void* d_ws, size_t ws_size,
                              hipStream_t stream) {
    const float* x   = (const float*)d_in[0];
    const float* w_q = (const float*)d_in[1];
    const float* s_q = (const float*)d_in[2];
    const float* b_q = (const float*)d_in[3];
    const float* w_k = (const float*)d_in[4];
    const float* s_k = (const float*)d_in[5];
    const float* b_k = (const float*)d_in[6];
    const float* w_v = (const float*)d_in[7];
    const float* s_v = (const float*)d_in[8];
    const float* b_v = (const float*)d_in[9];
    const float* w_o = (const float*)d_in[10];
    const float* s_o = (const float*)d_in[11];
    const float* b_o = (const float*)d_in[12];

    if (ws_size < (size_t)50331648) return;  // need 48 MB of scratch

    u16* ws     = (u16*)d_ws;
    u16* x_bf   = ws;                    // 4096*1024
    u16* wq_bf  = x_bf  + 4194304;       // 1024*1024 each
    u16* wk_bf  = wq_bf + 1048576;
    u16* wv_bf  = wk_bf + 1048576;
    u16* wo_bf  = wv_bf + 1048576;
    u16* q_ws   = wo_bf + 1048576;       // [32 bh][2048 s][64 d]
    u16* k_ws   = q_ws  + 4194304;
    u16* v_ws   = k_ws  + 4194304;       // [32 bh][64 d][2048 s]
    u16* ctx_ws = v_ws  + 4194304;       // [4096 t][1024]

    convert_kernel<<<dim3(8192), dim3(256), 0, stream>>>(x, w_q, w_k, w_v, w_o, ws);
    qkv_gemm<<<dim3(32, 8, 3), dim3(256), 0, stream>>>(x_bf, wq_bf, wk_bf, wv_bf,
                                                       s_q, s_k, s_v, b_q, b_k, b_v,
                                                       q_ws, k_ws, v_ws);
    attn_kernel<<<dim3(16, 32), dim3(256), 0, stream>>>(q_ws, k_ws, v_ws, ctx_ws);
    o_gemm<<<dim3(64, 8), dim3(256), 0, stream>>>(ctx_ws, wo_bf, s_o, b_o, (float*)d_out);
}